// Round 4
// baseline (126.343 us; speedup 1.0000x reference)
//
#include <hip/hip_runtime.h>
#include <math.h>
#include <float.h>

typedef unsigned long long u64;
typedef unsigned int u32;
typedef float nat_f4 __attribute__((ext_vector_type(4)));

#define NB 256       // batch
#define NQ 1000      // queries
#define NC 80        // classes
#define QC 80000     // NQ*NC per row
#define NQ4 (QC / 4) // 20000 float4s per row
#define TOPK 300
#define CAP 512      // candidate capacity = bitonic size (power of 2)
#define NTHREADS 1024
#define TAILN (NQ4 - 19 * NTHREADS)  // 544 threads have a 20th float4

// T=2.585: P(N(0,1) > 2.585) ~ 0.00487 -> ~390 +/- 20 candidates per row.
// Pass 0 is the bare collection scan. Scan structure: 3 memory rounds
// (8-deep, 8-deep, ~4-deep) instead of 4x4-deep + 3.5 serial single-load
// tail rounds — measured evidence (round 1: +16 VALU ops/elem cost +2.6us
// headline 1:1) says the scan is per-round latency-bound, so fewer/deeper
// rounds is the lever. Robustness against degenerate/poisoned data lives in
// a FALLBACK-ONLY histogram pass: if pass 0 misses [300,512] (never on real
// data), one counting pass over 8 fixed boundaries either pins a working
// threshold (1 guaranteed retry), proves none exists (bail), or brackets
// <=3 bisection passes. Worst case: 5 scans, not 24.
#define T_INIT 2.585f
#define MAX_EXTRA 3

__device__ __forceinline__ u64 shfl_xor_u64(u64 v, int mask) {
  int lo = __shfl_xor((int)(u32)(v & 0xFFFFFFFFull), mask, 64);
  int hi = __shfl_xor((int)(u32)(v >> 32), mask, 64);
  return ((u64)(u32)hi << 32) | (u64)(u32)lo;
}

// Non-temporal 16B load: __builtin_nontemporal_load needs a native vector
// type, not HIP's float4 class. Same layout, same global_load_dwordx4.
__device__ __forceinline__ float4 ld_nt(const float4* p) {
  nat_f4 v = __builtin_nontemporal_load(reinterpret_cast<const nat_f4*>(p));
  return make_float4(v.x, v.y, v.z, v.w);
}
__device__ __forceinline__ float4 ld_plain(const float4* p) { return *p; }

// key = (positive-float logit bits << 32) | (0xFFFFFFFF - flat_idx)
// Sigmoid is monotone => top-k on logits == top-k on scores; descending sort
// on this key reproduces jax.lax.top_k order (ties: lower index first).
__global__ __launch_bounds__(NTHREADS) void postproc_kernel(
    const float* __restrict__ logits,
    const float4* __restrict__ boxes,
    float* __restrict__ out) {
  const int row = blockIdx.x;
  const int tid = threadIdx.x;

  __shared__ u64 s_keys[CAP];
  __shared__ int s_cnt;
  __shared__ u32 s_hist[8];

  const float4* lp = (const float4*)logits + (size_t)row * NQ4;

  float T = T_INIT;
  int cnt = 0;

  auto filt = [&](float x, u32 idx) {
    if (x > T) {
      int pos = atomicAdd(&s_cnt, 1);
      if (pos < CAP)
        s_keys[pos] = ((u64)__float_as_uint(x) << 32) | (u64)(0xFFFFFFFFu - idx);
    }
  };

#define FILT4(v, i)                                                       \
  do {                                                                    \
    filt((v).x, 4u * (u32)(i));     filt((v).y, 4u * (u32)(i) + 1u);      \
    filt((v).z, 4u * (u32)(i) + 2u); filt((v).w, 4u * (u32)(i) + 3u);     \
  } while (0)

  // collection scan: 3 rounds. All loads of a round are issued before any
  // consumption (independent addresses), so waitcnt cascades vmcnt(7..0).
  // Lanes tid>=TAILN get a -FLT_MAX sentinel for the 20th float4: it can
  // never pass any threshold the fallback uses (T >= -30), so filt is
  // branch-free and the bogus index is never stored.
#define SCAN_BODY(LD)                                                     \
  do {                                                                    \
    { /* round A: k = 0..7, 8 loads in flight */                          \
      float4 a0 = LD(lp + tid);                                           \
      float4 a1 = LD(lp + tid + 1 * NTHREADS);                            \
      float4 a2 = LD(lp + tid + 2 * NTHREADS);                            \
      float4 a3 = LD(lp + tid + 3 * NTHREADS);                            \
      float4 a4 = LD(lp + tid + 4 * NTHREADS);                            \
      float4 a5 = LD(lp + tid + 5 * NTHREADS);                            \
      float4 a6 = LD(lp + tid + 6 * NTHREADS);                            \
      float4 a7 = LD(lp + tid + 7 * NTHREADS);                            \
      FILT4(a0, tid + 0 * NTHREADS); FILT4(a1, tid + 1 * NTHREADS);       \
      FILT4(a2, tid + 2 * NTHREADS); FILT4(a3, tid + 3 * NTHREADS);       \
      FILT4(a4, tid + 4 * NTHREADS); FILT4(a5, tid + 5 * NTHREADS);       \
      FILT4(a6, tid + 6 * NTHREADS); FILT4(a7, tid + 7 * NTHREADS);       \
    }                                                                     \
    { /* round B: k = 8..15 */                                            \
      float4 b0 = LD(lp + tid + 8 * NTHREADS);                            \
      float4 b1 = LD(lp + tid + 9 * NTHREADS);                            \
      float4 b2 = LD(lp + tid + 10 * NTHREADS);                           \
      float4 b3 = LD(lp + tid + 11 * NTHREADS);                           \
      float4 b4 = LD(lp + tid + 12 * NTHREADS);                           \
      float4 b5 = LD(lp + tid + 13 * NTHREADS);                           \
      float4 b6 = LD(lp + tid + 14 * NTHREADS);                           \
      float4 b7 = LD(lp + tid + 15 * NTHREADS);                           \
      FILT4(b0, tid + 8 * NTHREADS);  FILT4(b1, tid + 9 * NTHREADS);      \
      FILT4(b2, tid + 10 * NTHREADS); FILT4(b3, tid + 11 * NTHREADS);     \
      FILT4(b4, tid + 12 * NTHREADS); FILT4(b5, tid + 13 * NTHREADS);     \
      FILT4(b6, tid + 14 * NTHREADS); FILT4(b7, tid + 15 * NTHREADS);     \
    }                                                                     \
    { /* round C: k = 16..18 full + k = 19 predicated (tid < TAILN) */    \
      float4 c0 = LD(lp + tid + 16 * NTHREADS);                           \
      float4 c1 = LD(lp + tid + 17 * NTHREADS);                           \
      float4 c2 = LD(lp + tid + 18 * NTHREADS);                           \
      float4 c3 = make_float4(-FLT_MAX, -FLT_MAX, -FLT_MAX, -FLT_MAX);    \
      if (tid < TAILN) c3 = LD(lp + tid + 19 * NTHREADS);                 \
      FILT4(c0, tid + 16 * NTHREADS); FILT4(c1, tid + 17 * NTHREADS);     \
      FILT4(c2, tid + 18 * NTHREADS); FILT4(c3, tid + 19 * NTHREADS);     \
    }                                                                     \
  } while (0)

  // ---- pass 0: bare collection at T_INIT (the only pass on real data)
  if (tid == 0) s_cnt = 0;
  __syncthreads();
  SCAN_BODY(ld_nt);
  __syncthreads();
  cnt = s_cnt;

  if (!(cnt >= TOPK && cnt <= CAP)) {
    // ---- fallback A: counting pass over 8 fixed boundaries (no collection).
    // For N(0,1)x80000 counts ~{67k, 5345, 1820, 1112, 656, 372, 204, 77}.
    const float tb0 = -1.0f, tb1 = 1.5f, tb2 = 2.0f, tb3 = 2.2f;
    const float tb4 = 2.4f, tb5 = 2.6f, tb6 = 2.8f, tb7 = 3.1f;
    u32 h0 = 0, h1 = 0, h2 = 0, h3 = 0, h4 = 0, h5 = 0, h6 = 0, h7 = 0;
    if (tid < 8) s_hist[tid] = 0;
    for (int i = tid; i < NQ4; i += NTHREADS) {
      float4 v = lp[i];
      h0 += (v.x > tb0) + (v.y > tb0) + (v.z > tb0) + (v.w > tb0);
      h1 += (v.x > tb1) + (v.y > tb1) + (v.z > tb1) + (v.w > tb1);
      h2 += (v.x > tb2) + (v.y > tb2) + (v.z > tb2) + (v.w > tb2);
      h3 += (v.x > tb3) + (v.y > tb3) + (v.z > tb3) + (v.w > tb3);
      h4 += (v.x > tb4) + (v.y > tb4) + (v.z > tb4) + (v.w > tb4);
      h5 += (v.x > tb5) + (v.y > tb5) + (v.z > tb5) + (v.w > tb5);
      h6 += (v.x > tb6) + (v.y > tb6) + (v.z > tb6) + (v.w > tb6);
      h7 += (v.x > tb7) + (v.y > tb7) + (v.z > tb7) + (v.w > tb7);
    }
#pragma unroll
    for (int m = 32; m > 0; m >>= 1) {
      h0 += (u32)__shfl_xor((int)h0, m, 64);
      h1 += (u32)__shfl_xor((int)h1, m, 64);
      h2 += (u32)__shfl_xor((int)h2, m, 64);
      h3 += (u32)__shfl_xor((int)h3, m, 64);
      h4 += (u32)__shfl_xor((int)h4, m, 64);
      h5 += (u32)__shfl_xor((int)h5, m, 64);
      h6 += (u32)__shfl_xor((int)h6, m, 64);
      h7 += (u32)__shfl_xor((int)h7, m, 64);
    }
    __syncthreads();  // s_hist zeroing visible before atomics
    if ((tid & 63) == 0) {
      atomicAdd(&s_hist[0], h0); atomicAdd(&s_hist[1], h1);
      atomicAdd(&s_hist[2], h2); atomicAdd(&s_hist[3], h3);
      atomicAdd(&s_hist[4], h4); atomicAdd(&s_hist[5], h5);
      atomicAdd(&s_hist[6], h6); atomicAdd(&s_hist[7], h7);
    }
    __syncthreads();

    // uniform decision on every thread (s_hist identical for all)
    u32 C[8];
#pragma unroll
    for (int i = 0; i < 8; ++i) C[i] = s_hist[i];
    const float tbv[8] = {tb0, tb1, tb2, tb3, tb4, tb5, tb6, tb7};

    int exact = -1;
    float nT = T_INIT;
    float lo = -30.0f, hi = 40.0f;
#pragma unroll
    for (int i = 0; i < 8; ++i) {  // fully unrolled -> static indices only
      if (C[i] >= TOPK && C[i] <= CAP) { exact = i; nT = tbv[i]; }
      if (C[i] > CAP) lo = tbv[i];               // largest tb with count>CAP
      if (C[7 - i] < TOPK) hi = tbv[7 - i];      // smallest tb with count<TOPK
    }
    // state: 0 = exact threshold known (1 retry, guaranteed),
    //        1 = bracketed bisection, 2 = bail now (e.g. NaN poison: C[0]==0)
    int state = (exact >= 0) ? 0 : ((C[0] == 0) ? 2 : 1);
    if (state == 1) nT = 0.5f * (lo + hi);

    if (state != 2) {
      T = nT;
      for (int extra = 0; extra < MAX_EXTRA; ++extra) {
        __syncthreads();
        if (tid == 0) s_cnt = 0;
        __syncthreads();
        SCAN_BODY(ld_plain);
        __syncthreads();
        cnt = s_cnt;
        if (cnt >= TOPK && cnt <= CAP) break;
        if (state == 0) break;  // exact retry can't miss; belt-and-braces
        if (cnt < TOPK) hi = T; else lo = T;
        T = 0.5f * (lo + hi);
      }
    }
  }
  if (cnt > CAP) cnt = CAP;

  // ---- register bitonic sort, descending, CAP=512 keys on threads 0..511.
  // Strides <=32: __shfl_xor (no barriers, 39 half-stages).
  // Strides 64/128/256: LDS exchange (6 half-stages, 12 barriers).
  u64 key = 0;
  if (tid < CAP && tid < cnt) key = s_keys[tid];

  for (int k = 2; k <= CAP; k <<= 1) {
    for (int j = k >> 1; j > 0; j >>= 1) {
      if (j >= 64) {
        __syncthreads();
        if (tid < CAP) s_keys[tid] = key;
        __syncthreads();
        if (tid < CAP) {
          u64 other = s_keys[tid ^ j];
          bool iLower = (tid & j) == 0;
          bool dirAsc = (tid & k) != 0;  // k=CAP => all-descending final
          bool keepMin = (dirAsc == iLower);
          key = keepMin ? (key < other ? key : other)
                        : (key > other ? key : other);
        }
      } else if (tid < CAP) {  // wave-uniform branch (tids >=512 whole waves)
        u64 other = shfl_xor_u64(key, j);
        bool iLower = (tid & j) == 0;
        bool dirAsc = (tid & k) != 0;
        bool keepMin = (dirAsc == iLower);
        key = keepMin ? (key < other ? key : other)
                      : (key > other ? key : other);
      }
    }
  }

  // ---- epilogue: thread tid holds the rank-tid key in register
  if (tid < TOPK) {
    float* labels_out = out;                  // [NB, TOPK]
    float* boxes_out = out + NB * TOPK;       // [NB, TOPK, 4]
    float* scores_out = out + NB * TOPK * 5;  // [NB, TOPK]

    float lab = 0.0f, score = 0.0f;
    float4 bo = make_float4(0.0f, 0.0f, 0.0f, 0.0f);
    if (tid < cnt) {
      u32 idx = 0xFFFFFFFFu - (u32)(key & 0xFFFFFFFFull);
      float x = __uint_as_float((u32)(key >> 32));
      int q = (int)(idx / NC);
      int c = (int)(idx - (u32)q * NC);
      lab = (float)c;
      score = (float)(1.0 / (1.0 + exp(-(double)x)));  // exact f32 sigmoid
      float4 bb = boxes[(size_t)row * NQ + q];
      float hw = 0.5f * bb.z, hh = 0.5f * bb.w;
      bo.x = bb.x - hw;
      bo.y = bb.y - hh;
      bo.z = bb.x + hw;
      bo.w = bb.y + hh;
    }
    labels_out[row * TOPK + tid] = lab;
    scores_out[row * TOPK + tid] = score;
    ((float4*)boxes_out)[row * TOPK + tid] = bo;
  }
}

extern "C" void kernel_launch(void* const* d_in, const int* in_sizes, int n_in,
                              void* d_out, int out_size, void* d_ws, size_t ws_size,
                              hipStream_t stream) {
  const float* logits = (const float*)d_in[0];
  const float4* boxes = (const float4*)d_in[1];
  float* out = (float*)d_out;
  postproc_kernel<<<NB, NTHREADS, 0, stream>>>(logits, boxes, out);
}

// Round 5
// 122.859 us; speedup vs baseline: 1.0284x; 1.0284x over previous
//
#include <hip/hip_runtime.h>
#include <math.h>

typedef unsigned long long u64;
typedef unsigned int u32;
typedef float nat_f4 __attribute__((ext_vector_type(4)));

#define NB 256       // batch
#define NQ 1000      // queries
#define NC 80        // classes
#define QC 80000     // NQ*NC per row
#define NQ4 (QC / 4) // 20000 float4s per row
#define TOPK 300
#define CAP 512      // candidate capacity = bitonic size (power of 2)
#define NTHREADS 1024

// T=2.585: P(N(0,1) > 2.585) ~ 0.00487 -> ~390 +/- 20 candidates per row.
// Scan structure: 4x4-deep unrolled head + strided tail — measured best
// (123.07us headline vs 126.34 for 8-deep rounds; scan is chip-BW-bound at
// 16 waves/CU x 4-deep = 64KB in flight/CU >> ~22KB needed, so deeper
// pipelining only added overhead). Robustness against degenerate/poisoned
// data lives in a FALLBACK-ONLY histogram pass: if pass 0 misses [300,512]
// (never on real data), one counting pass over 8 fixed boundaries either
// pins a working threshold (1 guaranteed retry), proves none exists (bail),
// or brackets <=3 bisection passes. Worst case: 5 scans, not 24.
#define T_INIT 2.585f
#define MAX_EXTRA 3

__device__ __forceinline__ u64 shfl_xor_u64(u64 v, int mask) {
  int lo = __shfl_xor((int)(u32)(v & 0xFFFFFFFFull), mask, 64);
  int hi = __shfl_xor((int)(u32)(v >> 32), mask, 64);
  return ((u64)(u32)hi << 32) | (u64)(u32)lo;
}

// Non-temporal 16B load: __builtin_nontemporal_load needs a native vector
// type, not HIP's float4 class. Same layout, same global_load_dwordx4.
__device__ __forceinline__ float4 ld_nt(const float4* p) {
  nat_f4 v = __builtin_nontemporal_load(reinterpret_cast<const nat_f4*>(p));
  return make_float4(v.x, v.y, v.z, v.w);
}
__device__ __forceinline__ float4 ld_plain(const float4* p) { return *p; }

// key = (positive-float logit bits << 32) | (0xFFFFFFFF - flat_idx)
// Sigmoid is monotone => top-k on logits == top-k on scores; descending sort
// on this key reproduces jax.lax.top_k order (ties: lower index first).
__global__ __launch_bounds__(NTHREADS) void postproc_kernel(
    const float* __restrict__ logits,
    const float4* __restrict__ boxes,
    float* __restrict__ out) {
  const int row = blockIdx.x;
  const int tid = threadIdx.x;

  __shared__ u64 s_keys[CAP];
  __shared__ int s_cnt;
  __shared__ u32 s_hist[8];

  const float4* lp = (const float4*)logits + (size_t)row * NQ4;

  float T = T_INIT;
  int cnt = 0;

  auto filt = [&](float x, u32 idx) {
    if (x > T) {
      int pos = atomicAdd(&s_cnt, 1);
      if (pos < CAP)
        s_keys[pos] = ((u64)__float_as_uint(x) << 32) | (u64)(0xFFFFFFFFu - idx);
    }
  };

  // collection scan: 4x unrolled (16 independent loads' addresses known up
  // front). LD(p) is ld_nt on pass 0 (streaming, read-once) and ld_plain on
  // retries (let caches serve re-scans).
#define SCAN_BODY(LD)                                                     \
  do {                                                                    \
    for (int i = tid; i < 16384; i += 4 * NTHREADS) {                     \
      float4 v0 = LD(lp + i);                                             \
      float4 v1 = LD(lp + i + NTHREADS);                                  \
      float4 v2 = LD(lp + i + 2 * NTHREADS);                              \
      float4 v3 = LD(lp + i + 3 * NTHREADS);                              \
      filt(v0.x, 4 * i);     filt(v0.y, 4 * i + 1);                       \
      filt(v0.z, 4 * i + 2); filt(v0.w, 4 * i + 3);                       \
      int i1 = i + NTHREADS;                                              \
      filt(v1.x, 4 * i1);     filt(v1.y, 4 * i1 + 1);                     \
      filt(v1.z, 4 * i1 + 2); filt(v1.w, 4 * i1 + 3);                     \
      int i2 = i + 2 * NTHREADS;                                          \
      filt(v2.x, 4 * i2);     filt(v2.y, 4 * i2 + 1);                     \
      filt(v2.z, 4 * i2 + 2); filt(v2.w, 4 * i2 + 3);                     \
      int i3 = i + 3 * NTHREADS;                                          \
      filt(v3.x, 4 * i3);     filt(v3.y, 4 * i3 + 1);                     \
      filt(v3.z, 4 * i3 + 2); filt(v3.w, 4 * i3 + 3);                     \
    }                                                                     \
    for (int i = 16384 + tid; i < NQ4; i += NTHREADS) {                   \
      float4 v = LD(lp + i);                                              \
      filt(v.x, 4 * i);     filt(v.y, 4 * i + 1);                         \
      filt(v.z, 4 * i + 2); filt(v.w, 4 * i + 3);                         \
    }                                                                     \
  } while (0)

  // ---- pass 0: bare collection at T_INIT (the only pass on real data)
  if (tid == 0) s_cnt = 0;
  __syncthreads();
  SCAN_BODY(ld_nt);
  __syncthreads();
  cnt = s_cnt;

  if (!(cnt >= TOPK && cnt <= CAP)) {
    // ---- fallback A: counting pass over 8 fixed boundaries (no collection).
    // For N(0,1)x80000 counts ~{67k, 5345, 1820, 1112, 656, 372, 204, 77}.
    const float tb0 = -1.0f, tb1 = 1.5f, tb2 = 2.0f, tb3 = 2.2f;
    const float tb4 = 2.4f, tb5 = 2.6f, tb6 = 2.8f, tb7 = 3.1f;
    u32 h0 = 0, h1 = 0, h2 = 0, h3 = 0, h4 = 0, h5 = 0, h6 = 0, h7 = 0;
    if (tid < 8) s_hist[tid] = 0;
    for (int i = tid; i < NQ4; i += NTHREADS) {
      float4 v = lp[i];
      h0 += (v.x > tb0) + (v.y > tb0) + (v.z > tb0) + (v.w > tb0);
      h1 += (v.x > tb1) + (v.y > tb1) + (v.z > tb1) + (v.w > tb1);
      h2 += (v.x > tb2) + (v.y > tb2) + (v.z > tb2) + (v.w > tb2);
      h3 += (v.x > tb3) + (v.y > tb3) + (v.z > tb3) + (v.w > tb3);
      h4 += (v.x > tb4) + (v.y > tb4) + (v.z > tb4) + (v.w > tb4);
      h5 += (v.x > tb5) + (v.y > tb5) + (v.z > tb5) + (v.w > tb5);
      h6 += (v.x > tb6) + (v.y > tb6) + (v.z > tb6) + (v.w > tb6);
      h7 += (v.x > tb7) + (v.y > tb7) + (v.z > tb7) + (v.w > tb7);
    }
#pragma unroll
    for (int m = 32; m > 0; m >>= 1) {
      h0 += (u32)__shfl_xor((int)h0, m, 64);
      h1 += (u32)__shfl_xor((int)h1, m, 64);
      h2 += (u32)__shfl_xor((int)h2, m, 64);
      h3 += (u32)__shfl_xor((int)h3, m, 64);
      h4 += (u32)__shfl_xor((int)h4, m, 64);
      h5 += (u32)__shfl_xor((int)h5, m, 64);
      h6 += (u32)__shfl_xor((int)h6, m, 64);
      h7 += (u32)__shfl_xor((int)h7, m, 64);
    }
    __syncthreads();  // s_hist zeroing visible before atomics
    if ((tid & 63) == 0) {
      atomicAdd(&s_hist[0], h0); atomicAdd(&s_hist[1], h1);
      atomicAdd(&s_hist[2], h2); atomicAdd(&s_hist[3], h3);
      atomicAdd(&s_hist[4], h4); atomicAdd(&s_hist[5], h5);
      atomicAdd(&s_hist[6], h6); atomicAdd(&s_hist[7], h7);
    }
    __syncthreads();

    // uniform decision on every thread (s_hist identical for all)
    u32 C[8];
#pragma unroll
    for (int i = 0; i < 8; ++i) C[i] = s_hist[i];
    const float tbv[8] = {tb0, tb1, tb2, tb3, tb4, tb5, tb6, tb7};

    int exact = -1;
    float nT = T_INIT;
    float lo = -30.0f, hi = 40.0f;
#pragma unroll
    for (int i = 0; i < 8; ++i) {  // fully unrolled -> static indices only
      if (C[i] >= TOPK && C[i] <= CAP) { exact = i; nT = tbv[i]; }
      if (C[i] > CAP) lo = tbv[i];               // largest tb with count>CAP
      if (C[7 - i] < TOPK) hi = tbv[7 - i];      // smallest tb with count<TOPK
    }
    // state: 0 = exact threshold known (1 retry, guaranteed),
    //        1 = bracketed bisection, 2 = bail now (e.g. NaN poison: C[0]==0)
    int state = (exact >= 0) ? 0 : ((C[0] == 0) ? 2 : 1);
    if (state == 1) nT = 0.5f * (lo + hi);

    if (state != 2) {
      T = nT;
      for (int extra = 0; extra < MAX_EXTRA; ++extra) {
        __syncthreads();
        if (tid == 0) s_cnt = 0;
        __syncthreads();
        SCAN_BODY(ld_plain);
        __syncthreads();
        cnt = s_cnt;
        if (cnt >= TOPK && cnt <= CAP) break;
        if (state == 0) break;  // exact retry can't miss; belt-and-braces
        if (cnt < TOPK) hi = T; else lo = T;
        T = 0.5f * (lo + hi);
      }
    }
  }
  if (cnt > CAP) cnt = CAP;

  // ---- register bitonic sort, descending, CAP=512 keys on threads 0..511.
  // Strides <=32: __shfl_xor (no barriers, 39 half-stages).
  // Strides 64/128/256: LDS exchange (6 half-stages, 12 barriers).
  u64 key = 0;
  if (tid < CAP && tid < cnt) key = s_keys[tid];

  for (int k = 2; k <= CAP; k <<= 1) {
    for (int j = k >> 1; j > 0; j >>= 1) {
      if (j >= 64) {
        __syncthreads();
        if (tid < CAP) s_keys[tid] = key;
        __syncthreads();
        if (tid < CAP) {
          u64 other = s_keys[tid ^ j];
          bool iLower = (tid & j) == 0;
          bool dirAsc = (tid & k) != 0;  // k=CAP => all-descending final
          bool keepMin = (dirAsc == iLower);
          key = keepMin ? (key < other ? key : other)
                        : (key > other ? key : other);
        }
      } else if (tid < CAP) {  // wave-uniform branch (tids >=512 whole waves)
        u64 other = shfl_xor_u64(key, j);
        bool iLower = (tid & j) == 0;
        bool dirAsc = (tid & k) != 0;
        bool keepMin = (dirAsc == iLower);
        key = keepMin ? (key < other ? key : other)
                      : (key > other ? key : other);
      }
    }
  }

  // ---- epilogue: thread tid holds the rank-tid key in register
  if (tid < TOPK) {
    float* labels_out = out;                  // [NB, TOPK]
    float* boxes_out = out + NB * TOPK;       // [NB, TOPK, 4]
    float* scores_out = out + NB * TOPK * 5;  // [NB, TOPK]

    float lab = 0.0f, score = 0.0f;
    float4 bo = make_float4(0.0f, 0.0f, 0.0f, 0.0f);
    if (tid < cnt) {
      u32 idx = 0xFFFFFFFFu - (u32)(key & 0xFFFFFFFFull);
      float x = __uint_as_float((u32)(key >> 32));
      int q = (int)(idx / NC);
      int c = (int)(idx - (u32)q * NC);
      lab = (float)c;
      score = (float)(1.0 / (1.0 + exp(-(double)x)));  // exact f32 sigmoid
      float4 bb = boxes[(size_t)row * NQ + q];
      float hw = 0.5f * bb.z, hh = 0.5f * bb.w;
      bo.x = bb.x - hw;
      bo.y = bb.y - hh;
      bo.z = bb.x + hw;
      bo.w = bb.y + hh;
    }
    labels_out[row * TOPK + tid] = lab;
    scores_out[row * TOPK + tid] = score;
    ((float4*)boxes_out)[row * TOPK + tid] = bo;
  }
}

extern "C" void kernel_launch(void* const* d_in, const int* in_sizes, int n_in,
                              void* d_out, int out_size, void* d_ws, size_t ws_size,
                              hipStream_t stream) {
  const float* logits = (const float*)d_in[0];
  const float4* boxes = (const float4*)d_in[1];
  float* out = (float*)d_out;
  postproc_kernel<<<NB, NTHREADS, 0, stream>>>(logits, boxes, out);
}